// Round 7
// baseline (308.620 us; speedup 1.0000x reference)
//
#include <hip/hip_runtime.h>
#include <hip/hip_bf16.h>

#define N_NODES 100000
#define N_EDGES 1600000
#define DIM 64

#define TILE 4096
#define B1 ((N_EDGES + TILE - 1) / TILE)   // 391 partition blocks
#define K1 ((N_NODES + 255) / 256)         // 391 buckets of 256 nodes
#define CAP 4608                           // bucket mean 4096, sd 64 -> +8 sigma
#define PACKB ((N_NODES * DIM + 255) / 256)  // 25000

typedef __attribute__((ext_vector_type(8))) short bf16x8;
typedef __attribute__((ext_vector_type(4))) float f32x4;

#if defined(__has_builtin)
#if __has_builtin(__builtin_amdgcn_fdot2_f32_bf16)
#define HAVE_DOT2 1
typedef __attribute__((ext_vector_type(2))) __bf16 bf16x2v;
#endif
#endif

// ---------------- memory layout ----------------
// ws: At (32 KB) | cvec (1 KB) | hpack (25.6 MB) | cursor (K1 ints)  ~25.7 MB
// d_out zr half: records, K1*CAP*8 B = 14.4 MB (dead until epilogue writes)
// d_out zi half: zcat bf16 [N][128] (pull output; epilogue reads rows to regs
//                before overwriting them -- proven in rounds 4-6)

__device__ __forceinline__ unsigned pack_bf16x2(float lo, float hi) {
  unsigned ulo = (unsigned)__hip_bfloat16_raw(__float2bfloat16(lo)).x;
  unsigned uhi = (unsigned)__hip_bfloat16_raw(__float2bfloat16(hi)).x;
  return ulo | (uhi << 16);
}
__device__ __forceinline__ float unpack_lo(unsigned u) {
  return __int_as_float((int)(u << 16));
}
__device__ __forceinline__ float unpack_hi(unsigned u) {
  return __int_as_float((int)(u & 0xFFFF0000u));
}
__device__ __forceinline__ unsigned short f2bf(float x) {
  return __hip_bfloat16_raw(__float2bfloat16(x)).x;
}

// Fused setup: pack_h (blocks 0..PACKB-1) + combined epilogue operator:
// zr = zr_in@W1^T - zi_in@W2^T + (b1-b2)
// zi = zr_in@(W1^T W2^T) + zi_in@(W1^T - W2^T W2^T) + ((b1-b2)@W2^T + b1 + b2)
__global__ __launch_bounds__(256) void setup_fused_kernel(
    const float* __restrict__ h_real, const float* __restrict__ h_imag,
    unsigned* __restrict__ hpack, const float* __restrict__ W1,
    const float* __restrict__ b1, const float* __restrict__ W2,
    const float* __restrict__ b2, unsigned short* __restrict__ At,
    float* __restrict__ cvec) {
  const int bid = blockIdx.x;
  const int tid = threadIdx.x;
  if (bid < PACKB) {
    const int i = bid * 256 + tid;
    if (i < N_NODES * DIM) hpack[i] = pack_bf16x2(h_real[i], h_imag[i]);
    return;
  }
  const int idx = (bid - PACKB) * 256 + tid;
  if (idx < 128 * 128) {
    const int n = idx >> 7, k = idx & 127;
    float v;
    if (n < 64) {
      v = (k < 64) ? W1[n * 64 + k] : -W2[n * 64 + (k - 64)];
    } else {
      const int nn = n - 64;
      if (k < 64) {
        float s = 0.0f;
        for (int j = 0; j < 64; ++j) s += W1[j * 64 + k] * W2[nn * 64 + j];
        v = s;
      } else {
        const int kk = k - 64;
        float s = 0.0f;
        for (int j = 0; j < 64; ++j) s += W2[j * 64 + kk] * W2[nn * 64 + j];
        v = W1[nn * 64 + kk] - s;
      }
    }
    At[n * 128 + k] = f2bf(v);
  }
  if (idx < 128) {
    if (idx < 64) {
      cvec[idx] = b1[idx] - b2[idx];
    } else {
      const int nn = idx - 64;
      float s = 0.0f;
      for (int j = 0; j < 64; ++j) s += (b1[j] - b2[j]) * W2[nn * 64 + j];
      cvec[idx] = s + b1[nn] + b2[nn];
    }
  }
}

// Partition: per-tile LDS histogram over K1 buckets, ONE global atomicAdd per
// nonzero bucket reserves a contiguous run in that bucket's fixed region
// [b*CAP, (b+1)*CAP). Tile regrouped in LDS -> runs written contiguously.
// No global scan anywhere.
__global__ __launch_bounds__(512) void partition_kernel(
    const int* __restrict__ src, const int* __restrict__ dst,
    const float* __restrict__ dvec,
    const float* __restrict__ w_real, const float* __restrict__ w_imag,
    int* __restrict__ cursor, unsigned long long* __restrict__ records) {
  __shared__ unsigned long long stage[TILE];  // 32 KB
  __shared__ unsigned short sb[TILE];         // 8 KB
  __shared__ int lhist[512];
  __shared__ int lbase[512];
  __shared__ int lcur[512];
  __shared__ int gbase[512];
  const int tid = threadIdx.x;
  const int blk = blockIdx.x;
  const int e0 = blk * TILE;
  const int cnt_t = min(TILE, N_EDGES - e0);

  lhist[tid] = 0;
  __syncthreads();
  for (int j = tid; j < cnt_t; j += 512) atomicAdd(&lhist[dst[e0 + j] >> 8], 1);
  __syncthreads();
  const int myc = lhist[tid];
  __syncthreads();
#pragma unroll
  for (int off = 1; off < 512; off <<= 1) {
    int v = (tid >= off) ? lhist[tid - off] : 0;
    __syncthreads();
    lhist[tid] += v;
    __syncthreads();
  }
  {
    const int ex = lhist[tid] - myc;
    lbase[tid] = ex;
    lcur[tid] = ex;
    gbase[tid] = (tid < K1 && myc > 0) ? atomicAdd(&cursor[tid], myc) : 0;
  }
  __syncthreads();

  for (int j = tid; j < cnt_t; j += 512) {
    const int e = e0 + j;
    const int t = dst[e];
    const int s = src[e];
    const int b = t >> 8;
    const float ds = dvec[s];
    const unsigned lo = (unsigned)s | ((unsigned)(t & 255) << 17);
    const unsigned hi = pack_bf16x2(ds * w_real[e], ds * w_imag[e]);
    const int r = atomicAdd(&lcur[b], 1);
    stage[r] = ((unsigned long long)hi << 32) | lo;
    sb[r] = (unsigned short)b;
  }
  __syncthreads();
  for (int i = tid; i < cnt_t; i += 512) {
    const int b = sb[i];
    const int pos = gbase[b] + (i - lbase[b]);
    if (pos < CAP) records[(size_t)b * CAP + pos] = stage[i];
  }
}

// One block per bucket: stage region in LDS, per-node count + 256-scan, build
// sorted index array, then 8 waves process 32 nodes each with NO further
// barriers (the round-6 regression was the 16-wave barrier coupling).
__global__ __launch_bounds__(512) void pull_bucket_kernel(
    const unsigned long long* __restrict__ records, const int* __restrict__ cursor,
    const float* __restrict__ dvec, const unsigned* __restrict__ hpack,
    unsigned short* __restrict__ zcat) {
  __shared__ unsigned long long stage[CAP];  // 36.9 KB
  __shared__ unsigned short sidx[CAP];       // 9.2 KB
  __shared__ int ncnt[256];
  __shared__ int noff[256];
  __shared__ int ncur[256];

  const int tid = threadIdx.x;
  const int b = blockIdx.x;
  const int cnt = min(cursor[b], CAP);
  const unsigned long long* __restrict__ reg = records + (size_t)b * CAP;

  if (tid < 256) ncnt[tid] = 0;
  __syncthreads();
  for (int i = tid; i < cnt; i += 512) {
    const unsigned long long rec = reg[i];
    stage[i] = rec;
    atomicAdd(&ncnt[((unsigned)rec >> 17) & 255], 1);
  }
  __syncthreads();
  // inclusive scan of ncnt (threads 0..255) -> noff (exclusive), ncur
  int myc = 0;
  if (tid < 256) {
    myc = ncnt[tid];
    noff[tid] = myc;
  }
  __syncthreads();
#pragma unroll
  for (int off = 1; off < 256; off <<= 1) {
    int v = 0;
    if (tid < 256 && tid >= off) v = noff[tid - off];
    __syncthreads();
    if (tid < 256) noff[tid] += v;
    __syncthreads();
  }
  if (tid < 256) {
    const int ex = noff[tid] - myc;
    noff[tid] = ex;
    ncur[tid] = ex;
  }
  __syncthreads();
  for (int i = tid; i < cnt; i += 512) {
    const int nl = ((unsigned)stage[i] >> 17) & 255;
    const int r = atomicAdd(&ncur[nl], 1);
    sidx[r] = (unsigned short)i;
  }
  __syncthreads();

  // barrier-free processing: wave w handles node-locals w, w+8, ...
  const int lane = tid & 63;
  const int wave = tid >> 6;
  const unsigned* __restrict__ hl = hpack + lane;

  for (int nl = wave; nl < 256; nl += 8) {
    const int n = (b << 8) + nl;
    if (n >= N_NODES) break;
    const int s0 = noff[nl];
    const int e1 = s0 + ncnt[nl];

    float sr = 0.0f, si = 0.0f;
    int p = s0;
#if HAVE_DOT2
#define ACC(WW, HH)                                                      \
  {                                                                      \
    const unsigned wneg = (WW) ^ 0x80000000u;          /* (er,-ei) */    \
    const unsigned wswp = ((WW) >> 16) | ((WW) << 16); /* (ei, er) */    \
    const bf16x2v hv = __builtin_bit_cast(bf16x2v, HH);                  \
    sr = __builtin_amdgcn_fdot2_f32_bf16(__builtin_bit_cast(bf16x2v, wneg), \
                                         hv, sr, false);                 \
    si = __builtin_amdgcn_fdot2_f32_bf16(__builtin_bit_cast(bf16x2v, wswp), \
                                         hv, si, false);                 \
  }
#else
#define ACC(WW, HH)                                                      \
  {                                                                      \
    const float er = unpack_lo(WW), ei = unpack_hi(WW);                  \
    const float hr = unpack_lo(HH), hi = unpack_hi(HH);                  \
    sr += er * hr - ei * hi;                                             \
    si += ei * hr + er * hi;                                             \
  }
#endif
    for (; p + 4 <= e1; p += 4) {
      const int i0 = sidx[p + 0];
      const int i1 = sidx[p + 1];
      const int i2 = sidx[p + 2];
      const int i3 = sidx[p + 3];
      const unsigned long long r0 = stage[i0];
      const unsigned long long r1 = stage[i1];
      const unsigned long long r2 = stage[i2];
      const unsigned long long r3 = stage[i3];
      const unsigned h0 = hl[(size_t)((unsigned)r0 & 0x1FFFF) * DIM];
      const unsigned h1 = hl[(size_t)((unsigned)r1 & 0x1FFFF) * DIM];
      const unsigned h2 = hl[(size_t)((unsigned)r2 & 0x1FFFF) * DIM];
      const unsigned h3 = hl[(size_t)((unsigned)r3 & 0x1FFFF) * DIM];
      ACC((unsigned)(r0 >> 32), h0)
      ACC((unsigned)(r1 >> 32), h1)
      ACC((unsigned)(r2 >> 32), h2)
      ACC((unsigned)(r3 >> 32), h3)
    }
    for (; p < e1; ++p) {
      const unsigned long long r0 = stage[sidx[p]];
      const unsigned h0 = hl[(size_t)((unsigned)r0 & 0x1FFFF) * DIM];
      ACC((unsigned)(r0 >> 32), h0)
    }
#undef ACC

    const float dn = dvec[n];
    zcat[(size_t)n * 128 + lane] = f2bf(dn * sr);
    zcat[(size_t)n * 128 + 64 + lane] = f2bf(dn * si);
  }
}

// MFMA epilogue (round-4 proven). zcat aliases the zi half of d_out; each wave
// loads its 16 zcat rows into regs before storing those same rows.
__global__ __launch_bounds__(256) void mfma_epilogue_kernel(
    const unsigned short* zcat, const unsigned short* __restrict__ At,
    const float* __restrict__ cvec, float* zr_out, float* zi_out) {
  const int lane = threadIdx.x & 63;
  const int tile = blockIdx.x * (blockDim.x >> 6) + (threadIdx.x >> 6);
  if (tile >= N_NODES / 16) return;
  const int node0 = tile * 16;
  const int m = lane & 15;
  const int q = lane >> 4;

  bf16x8 a[4];
  const unsigned short* arow = zcat + (size_t)(node0 + m) * 128 + q * 8;
#pragma unroll
  for (int c = 0; c < 4; ++c)
    a[c] = *reinterpret_cast<const bf16x8*>(arow + c * 32);

  f32x4 acc[8];
#pragma unroll
  for (int t = 0; t < 8; ++t) {
    acc[t] = (f32x4){0.f, 0.f, 0.f, 0.f};
    const unsigned short* brow = At + (size_t)(t * 16 + m) * 128 + q * 8;
#pragma unroll
    for (int c = 0; c < 4; ++c) {
      bf16x8 bfrag = *reinterpret_cast<const bf16x8*>(brow + c * 32);
      acc[t] = __builtin_amdgcn_mfma_f32_16x16x32_bf16(a[c], bfrag, acc[t], 0, 0, 0);
    }
  }

#pragma unroll
  for (int t = 0; t < 8; ++t) {
    const int nf = t * 16 + m;
    const float bias = cvec[nf];
    float* outp = (nf < 64) ? zr_out : zi_out;
    const int nn = nf & 63;
#pragma unroll
    for (int r = 0; r < 4; ++r) {
      const int node = node0 + q * 4 + r;
      outp[(size_t)node * 64 + nn] = acc[t][r] + bias;
    }
  }
}

extern "C" void kernel_launch(void* const* d_in, const int* in_sizes, int n_in,
                              void* d_out, int out_size, void* d_ws, size_t ws_size,
                              hipStream_t stream) {
  const float* h_real = (const float*)d_in[0];
  const float* h_imag = (const float*)d_in[1];
  const float* dvec   = (const float*)d_in[2];
  const float* w_real = (const float*)d_in[3];
  const float* w_imag = (const float*)d_in[4];
  const int*   src    = (const int*)d_in[5];
  const int*   dst    = (const int*)d_in[6];
  const float* W1     = (const float*)d_in[7];
  const float* b1     = (const float*)d_in[8];
  const float* W2     = (const float*)d_in[9];
  const float* b2     = (const float*)d_in[10];

  char* ws = (char*)d_ws;
  unsigned short* At = (unsigned short*)ws;                  // 32 KB
  float* cvec = (float*)(ws + 128 * 128 * 2);                // 1 KB
  unsigned* hpack = (unsigned*)(ws + 33792);                 // 25.6 MB
  int* cursor = (int*)(ws + 33792 + (size_t)N_NODES * DIM * 4);  // K1 ints

  float* zr_out = (float*)d_out;
  float* zi_out = zr_out + (size_t)N_NODES * DIM;
  unsigned long long* records = (unsigned long long*)zr_out;  // 14.4 MB
  unsigned short* zcat = (unsigned short*)zi_out;             // 25.6 MB

  hipMemsetAsync(cursor, 0, (size_t)K1 * sizeof(int), stream);

  setup_fused_kernel<<<PACKB + 64, 256, 0, stream>>>(h_real, h_imag, hpack, W1,
                                                     b1, W2, b2, At, cvec);
  partition_kernel<<<B1, 512, 0, stream>>>(src, dst, dvec, w_real, w_imag,
                                           cursor, records);
  pull_bucket_kernel<<<K1, 512, 0, stream>>>(records, cursor, dvec, hpack, zcat);

  const int tiles = N_NODES / 16;  // 6250
  mfma_epilogue_kernel<<<(tiles + 3) / 4, 256, 0, stream>>>(zcat, At, cvec,
                                                            zr_out, zi_out);
}